// Round 4
// baseline (558.622 us; speedup 1.0000x reference)
//
#include <hip/hip_runtime.h>

#define B_ 8
#define T_ 24
#define N_ 4096
#define FI 64
#define HH 128
#define CC 192
#define COLS 128  // 1 block/CU; 2x work per barrier vs COLS=64 (amortize stalls, 2x ILP)
#define SX 72    // xT stride (bf16): 144B = 16B-aligned; 36 dw ≡ 4 mod 32 -> minimal-bank b128
#define SH 136   // hT stride (bf16): 272B = 16B-aligned; 68 dw ≡ 4 mod 32
#define SC2 136  // cT stride (bf16): same

typedef __bf16 bf16_t;
typedef bf16_t bf16x8 __attribute__((ext_vector_type(8)));
typedef bf16_t bf16x4 __attribute__((ext_vector_type(4)));
typedef float  f32x4  __attribute__((ext_vector_type(4)));

#define LOG2E 1.4426950408889634f

static __device__ __forceinline__ f32x4 mfma16(bf16x8 a, bf16x8 b, f32x4 c) {
    return __builtin_amdgcn_mfma_f32_16x16x32_bf16(a, b, c, 0, 0, 0);
}
static __device__ __forceinline__ float fast_rcp(float v) {
    return __builtin_amdgcn_rcpf(v);    // v_rcp_f32 (~1 ulp)
}
static __device__ __forceinline__ float fast_exp2(float v) {
    return __builtin_amdgcn_exp2f(v);   // v_exp_f32 (2^x)
}
// LDS-only drain barrier (no vmem ordering needed at any barrier here).
#define BAR() asm volatile("s_waitcnt lgkmcnt(0)\n\ts_barrier" ::: "memory")

// Wave/row assignment (8 waves, 128 cols):
//   gates (256 rows): wave w owns M-tiles {w} (r rows) and {8+w} (z rows), all 8 col-tiles
//   cand  (128 rows): wave w owns M-tile  {w}, all 8 col-tiles
//   => the lane computing cand(ch,col) also holds r(ch,col), z(ch,col), h(ch,col)
//      in registers: no LDS round-trip for z or fp32-h.
//   out   (64 rows): wave w -> M-tile w>>1, N-tiles (w&1)*4+{0..3}
//
// Gate weights/bias pre-scaled by -log2e, cand by -2*log2e at load:
//   sigma(a) = rcp(1 + exp2(gtilde)); tanh(v) = 2*rcp(1 + exp2(ctilde)) - 1
//
// __launch_bounds__(512, 2): an 8-wave block NEEDS 2 waves/SIMD co-resident ->
// VGPR cap 256 (est. usage ~240). (512,4) spilled weights (R2: FETCH 103MB->1.1GB).
//
// 2-barrier schedule (x double-buffered):
//   [B_h] out(t-1) ; gates(t) ; sigmoid -> cT
//   [B_c] stage x_{t+1} -> xT[buf^1]; prefetch x_{t+2}; cand(t); tanh -> hT
__global__ __launch_bounds__(512, 2) void mgru_kernel(
    const float* __restrict__ x,
    const float* __restrict__ gate_w,
    const float* __restrict__ gate_b,
    const float* __restrict__ cand_w,
    const float* __restrict__ cand_b,
    const float* __restrict__ out_w,
    const float* __restrict__ out_b,
    float* __restrict__ out)
{
    __shared__ __align__(16) bf16_t xT[2][COLS * SX];  // [buf][col][ch 0..63]  x_t (bf16)
    __shared__ __align__(16) bf16_t hT[COLS * SH];     // [col][ch 0..127]      h   (bf16)
    __shared__ __align__(16) bf16_t cT[COLS * SC2];    // [col][ch 0..127]      r*h (bf16)

    const int tid  = threadIdx.x;
    const int wave = tid >> 6;          // 0..7
    const int lane = tid & 63;
    const int quad = lane >> 4;
    const int l16  = lane & 15;

    const int bb = blockIdx.x >> 5;           // batch
    const int n0 = (blockIdx.x & 31) * COLS;  // column tile base

    // h0 = 0
    for (int i = tid; i < COLS * HH; i += 512) {
        const int col = i >> 7, ch = i & (HH - 1);
        hT[col * SH + ch] = (bf16_t)0.0f;
    }

    // ---- weights -> register A-fragments (lane holds A[m0+l16][k0+quad*8+j]) ----
    bf16x8 gA[2][6];   // scaled by -log2e
    #pragma unroll
    for (int p = 0; p < 2; ++p) {
        const int m = p * 128 + wave * 16 + l16;
        #pragma unroll
        for (int kt = 0; kt < 6; ++kt) {
            bf16x8 f;
            #pragma unroll
            for (int j = 0; j < 8; ++j)
                f[j] = (bf16_t)(gate_w[(m * CC + kt * 32 + quad * 8 + j) * 2 + 1] * (-LOG2E));
            gA[p][kt] = f;
        }
    }
    bf16x8 cA[6];      // scaled by -2*log2e
    {
        const int m = wave * 16 + l16;
        #pragma unroll
        for (int kt = 0; kt < 6; ++kt) {
            bf16x8 f;
            #pragma unroll
            for (int j = 0; j < 8; ++j)
                f[j] = (bf16_t)(cand_w[(m * CC + kt * 32 + quad * 8 + j) * 2 + 1] * (-2.0f * LOG2E));
            cA[kt] = f;
        }
    }
    bf16x8 oA[4];
    {
        const int m = (wave >> 1) * 16 + l16;
        #pragma unroll
        for (int kt = 0; kt < 4; ++kt) {
            bf16x8 f;
            #pragma unroll
            for (int j = 0; j < 8; ++j)
                f[j] = (bf16_t)out_w[m * HH + kt * 32 + quad * 8 + j];
            oA[kt] = f;
        }
    }

    // ---- biases -> accumulator-init registers (same scales) ----
    f32x4 gBr, gBz, cB, oB;
    #pragma unroll
    for (int r = 0; r < 4; ++r) {
        gBr[r] = gate_b[wave * 16 + quad * 4 + r] * (-LOG2E);
        gBz[r] = gate_b[128 + wave * 16 + quad * 4 + r] * (-LOG2E);
        cB[r]  = cand_b[wave * 16 + quad * 4 + r] * (-2.0f * LOG2E);
        oB[r]  = out_b[(wave >> 1) * 16 + quad * 4 + r];
    }

    // fp32 master h: hreg[nt][r] = h[wave*16+quad*4+r][nt*16+l16], nt=0..7
    f32x4 hreg[8];
    #pragma unroll
    for (int nt = 0; nt < 8; ++nt) hreg[nt] = f32x4{0.f, 0.f, 0.f, 0.f};

    const int xcol = tid >> 2;          // 0..127
    const int xcg  = (tid & 3) * 16;    // 16-float group of the 64 features
    const float* xbase = x   + ((size_t)bb * T_ * N_ + n0) * FI;
    float*       obase = out + ((size_t)bb * T_ * N_ + n0) * FI;

    // prologue: load + stage x_0, prefetch x_1
    f32x4 p0 = *(const f32x4*)(xbase + xcol * FI + xcg);
    f32x4 p1 = *(const f32x4*)(xbase + xcol * FI + xcg + 4);
    f32x4 p2 = *(const f32x4*)(xbase + xcol * FI + xcg + 8);
    f32x4 p3 = *(const f32x4*)(xbase + xcol * FI + xcg + 12);
    {
        bf16x8 xv, xw;
        xv[0] = (bf16_t)p0[0]; xv[1] = (bf16_t)p0[1];
        xv[2] = (bf16_t)p0[2]; xv[3] = (bf16_t)p0[3];
        xv[4] = (bf16_t)p1[0]; xv[5] = (bf16_t)p1[1];
        xv[6] = (bf16_t)p1[2]; xv[7] = (bf16_t)p1[3];
        xw[0] = (bf16_t)p2[0]; xw[1] = (bf16_t)p2[1];
        xw[2] = (bf16_t)p2[2]; xw[3] = (bf16_t)p2[3];
        xw[4] = (bf16_t)p3[0]; xw[5] = (bf16_t)p3[1];
        xw[6] = (bf16_t)p3[2]; xw[7] = (bf16_t)p3[3];
        *(bf16x8*)&xT[0][xcol * SX + xcg]     = xv;
        *(bf16x8*)&xT[0][xcol * SX + xcg + 8] = xw;
    }
    {
        const float* xp = xbase + (size_t)1 * N_ * FI + xcol * FI + xcg;
        p0 = *(const f32x4*)xp;
        p1 = *(const f32x4*)(xp + 4);
        p2 = *(const f32x4*)(xp + 8);
        p3 = *(const f32x4*)(xp + 12);
    }
    BAR();                                             // x_0, h_0 ready

    int buf = 0;
    for (int t = 0; t < T_; ++t) {
        const bf16_t* __restrict__ xcur = xT[buf];

        // ---- gates = Wg~ @ [x_t; h_{t-1}]  (8 col-tiles) ----
        f32x4 ar[8], az[8];
        #pragma unroll
        for (int nt = 0; nt < 8; ++nt) { ar[nt] = gBr; az[nt] = gBz; }
        __builtin_amdgcn_s_setprio(1);
        #pragma unroll
        for (int kt = 0; kt < 6; ++kt) {
            const int ko = kt * 32 + quad * 8;
            #pragma unroll
            for (int nt = 0; nt < 8; ++nt) {
                bf16x8 b = (kt < 2)
                    ? *(const bf16x8*)&xcur[(nt * 16 + l16) * SX + ko]
                    : *(const bf16x8*)&hT[(nt * 16 + l16) * SH + (ko - FI)];
                ar[nt] = mfma16(gA[0][kt], b, ar[nt]);
                az[nt] = mfma16(gA[1][kt], b, az[nt]);
            }
        }
        __builtin_amdgcn_s_setprio(0);

        // sigmoid: sigma = rcp(1 + exp2(gtilde)); r*h -> cT; z stays in registers
        f32x4 zreg[8];
        #pragma unroll
        for (int nt = 0; nt < 8; ++nt) {
            bf16x4 w;
            #pragma unroll
            for (int r = 0; r < 4; ++r) {
                const float rr = fast_rcp(1.0f + fast_exp2(ar[nt][r]));
                zreg[nt][r]    = fast_rcp(1.0f + fast_exp2(az[nt][r]));
                w[r] = (bf16_t)(rr * hreg[nt][r]);
            }
            *(bf16x4*)&cT[(nt * 16 + l16) * SC2 + wave * 16 + quad * 4] = w;
        }
        BAR();                                         // B_c: r*h ready

        // ---- stage x_{t+1} -> other buffer; prefetch x_{t+2} (overlaps cand) ----
        {
            bf16x8 xv, xw;
            xv[0] = (bf16_t)p0[0]; xv[1] = (bf16_t)p0[1];
            xv[2] = (bf16_t)p0[2]; xv[3] = (bf16_t)p0[3];
            xv[4] = (bf16_t)p1[0]; xv[5] = (bf16_t)p1[1];
            xv[6] = (bf16_t)p1[2]; xv[7] = (bf16_t)p1[3];
            xw[0] = (bf16_t)p2[0]; xw[1] = (bf16_t)p2[1];
            xw[2] = (bf16_t)p2[2]; xw[3] = (bf16_t)p2[3];
            xw[4] = (bf16_t)p3[0]; xw[5] = (bf16_t)p3[1];
            xw[6] = (bf16_t)p3[2]; xw[7] = (bf16_t)p3[3];
            *(bf16x8*)&xT[buf ^ 1][xcol * SX + xcg]     = xv;
            *(bf16x8*)&xT[buf ^ 1][xcol * SX + xcg + 8] = xw;
        }
        {
            const int tn = (t + 2 < T_) ? t + 2 : T_ - 1;
            const float* xp = xbase + (size_t)tn * N_ * FI + xcol * FI + xcg;
            p0 = *(const f32x4*)xp;
            p1 = *(const f32x4*)(xp + 4);
            p2 = *(const f32x4*)(xp + 8);
            p3 = *(const f32x4*)(xp + 12);
        }

        // ---- cand = Wc~ @ [x_t; r*h] ----
        f32x4 cc[8];
        #pragma unroll
        for (int nt = 0; nt < 8; ++nt) cc[nt] = cB;
        __builtin_amdgcn_s_setprio(1);
        #pragma unroll
        for (int kt = 0; kt < 6; ++kt) {
            const int ko = kt * 32 + quad * 8;
            #pragma unroll
            for (int nt = 0; nt < 8; ++nt) {
                bf16x8 b = (kt < 2)
                    ? *(const bf16x8*)&xcur[(nt * 16 + l16) * SX + ko]
                    : *(const bf16x8*)&cT[(nt * 16 + l16) * SC2 + (ko - FI)];
                cc[nt] = mfma16(cA[kt], b, cc[nt]);
            }
        }
        __builtin_amdgcn_s_setprio(0);

        // tanh(v) = 2*rcp(1+exp2(ctilde)) - 1 ; state update; write bf16 h_t
        #pragma unroll
        for (int nt = 0; nt < 8; ++nt) {
            bf16x4 hw;
            #pragma unroll
            for (int r = 0; r < 4; ++r) {
                const float q  = fast_rcp(1.0f + fast_exp2(cc[nt][r]));
                const float ht = fmaf(2.0f, q, -1.0f);
                const float z  = zreg[nt][r];
                const float h  = hreg[nt][r];
                const float hn = fmaf(z, ht - h, h);   // (1-z)h + z*ht
                hreg[nt][r] = hn;
                hw[r] = (bf16_t)hn;
            }
            *(bf16x4*)&hT[(nt * 16 + l16) * SH + wave * 16 + quad * 4] = hw;
        }
        BAR();                                         // B_h: h_t (and x_{t+1}) ready

        // ---- o = relu(Wo @ h_t + b) -> direct global store ----
        {
            f32x4 oa[4];
            #pragma unroll
            for (int j = 0; j < 4; ++j) oa[j] = oB;
            const int nb = (wave & 1) * 4;
            __builtin_amdgcn_s_setprio(1);
            #pragma unroll
            for (int kt = 0; kt < 4; ++kt) {
                const int ko = kt * 32 + quad * 8;
                #pragma unroll
                for (int j = 0; j < 4; ++j) {
                    bf16x8 b = *(const bf16x8*)&hT[((nb + j) * 16 + l16) * SH + ko];
                    oa[j] = mfma16(oA[kt], b, oa[j]);
                }
            }
            __builtin_amdgcn_s_setprio(0);
            #pragma unroll
            for (int j = 0; j < 4; ++j) {
                const int col = (nb + j) * 16 + l16;
                float* op = obase + (size_t)t * N_ * FI + col * FI + (wave >> 1) * 16 + quad * 4;
                f32x4 o;
                #pragma unroll
                for (int r = 0; r < 4; ++r) o[r] = fmaxf(oa[j][r], 0.0f);
                *(f32x4*)op = o;
            }
        }
        buf ^= 1;
    }
}

extern "C" void kernel_launch(void* const* d_in, const int* in_sizes, int n_in,
                              void* d_out, int out_size, void* d_ws, size_t ws_size,
                              hipStream_t stream) {
    (void)in_sizes; (void)n_in; (void)d_ws; (void)ws_size; (void)out_size;
    const float* x      = (const float*)d_in[0];
    const float* gate_w = (const float*)d_in[1];
    const float* gate_b = (const float*)d_in[2];
    const float* cand_w = (const float*)d_in[3];
    const float* cand_b = (const float*)d_in[4];
    const float* out_w  = (const float*)d_in[5];
    const float* out_b  = (const float*)d_in[6];
    float* out = (float*)d_out;
    mgru_kernel<<<dim3(B_ * (N_ / COLS)), dim3(512), 0, stream>>>(
        x, gate_w, gate_b, cand_w, cand_b, out_w, out_b, out);
}

// Round 5
// 549.105 us; speedup vs baseline: 1.0173x; 1.0173x over previous
//
#include <hip/hip_runtime.h>

#define B_ 8
#define T_ 24
#define N_ 4096
#define FI 64
#define HH 128
#define CC 192
#define COLS 64
#define SX 72    // xT stride (bf16): 144B = 16B-aligned; 36 dw ≡ 4 mod 32 -> minimal-bank b128
#define SH 136   // hT stride (bf16): 272B = 16B-aligned; 68 dw ≡ 4 mod 32
#define SC2 136  // cT stride (bf16): same

typedef __bf16 bf16_t;
typedef bf16_t bf16x8 __attribute__((ext_vector_type(8)));
typedef bf16_t bf16x4 __attribute__((ext_vector_type(4)));
typedef float  f32x4  __attribute__((ext_vector_type(4)));

#define LOG2E 1.4426950408889634f

static __device__ __forceinline__ f32x4 mfma16(bf16x8 a, bf16x8 b, f32x4 c) {
    return __builtin_amdgcn_mfma_f32_16x16x32_bf16(a, b, c, 0, 0, 0);
}
static __device__ __forceinline__ float fast_rcp(float v) {
    return __builtin_amdgcn_rcpf(v);    // v_rcp_f32 (~1 ulp)
}
static __device__ __forceinline__ float fast_exp2(float v) {
    return __builtin_amdgcn_exp2f(v);   // v_exp_f32 (2^x)
}
// LDS-only drain barrier (no vmem ordering needed at any barrier here).
#define BAR() asm volatile("s_waitcnt lgkmcnt(0)\n\ts_barrier" ::: "memory")

// COLUMN-SPLIT wave ownership (8 waves = 4 row-groups x 2 col-groups):
//   rg = wave>>1, cg = wave&1. Wave covers col-tiles nt in {2cg, 2cg+1}.
//   gates (256 rows): wave owns r-tiles {2rg,2rg+1} and z-tiles {8+2rg,8+2rg+1}
//                     -> 4 M x 2 nt x 6 kt = 48 mfma, but only 12 B-reads (reuse 4)
//   cand  (128 rows): wave owns tiles {2rg,2rg+1} -> 24 mfma, 12 B-reads (reuse 2)
//   out   ( 64 rows): wave owns M-tile rg, nt {2cg,2cg+1} -> 8 mfma, 8 reads
//   z/h locality preserved: the lane computing cand(ch,col) holds z,h(ch,col).
//   LDS reads/wave/step: 56 -> 39 (biases add 7 broadcast reads; B-reads 32).
//
// Weights 160 VGPR in registers; biases live in LDS (f32, pre-scaled).
// __launch_bounds__(512,1): VGPR cap >= 256 under either semantics of arg2
// (R2/R4 evidence: arg behaves as blocks/CU for 8-wave blocks: caps 64/128).
// Peak usage est. ~235. WATCH FETCH_SIZE: >150 MB means spill -> revert.
//
// Gate weights/bias pre-scaled by -log2e, cand by -2*log2e:
//   sigma(a) = rcp(1 + exp2(gtilde)); tanh(v) = 2*rcp(1 + exp2(ctilde)) - 1
//
// 2-barrier schedule (x double-buffered):
//   [B_h] out(t-1) ; gates(t) ; sigmoid -> cT
//   [B_c] stage x_{t+1} -> xT[buf^1]; prefetch x_{t+2}; cand(t); tanh -> hT
__global__ __launch_bounds__(512, 1) void mgru_kernel(
    const float* __restrict__ x,
    const float* __restrict__ gate_w,
    const float* __restrict__ gate_b,
    const float* __restrict__ cand_w,
    const float* __restrict__ cand_b,
    const float* __restrict__ out_w,
    const float* __restrict__ out_b,
    float* __restrict__ out)
{
    __shared__ __align__(16) bf16_t xT[2][COLS * SX];  // [buf][col][ch 0..63]  x_t (bf16)
    __shared__ __align__(16) bf16_t hT[COLS * SH];     // [col][ch 0..127]      h   (bf16)
    __shared__ __align__(16) bf16_t cT[COLS * SC2];    // [col][ch 0..127]      r*h (bf16)
    __shared__ __align__(16) float  biasG[256];        // gate bias * -log2e
    __shared__ __align__(16) float  biasC[128];        // cand bias * -2log2e
    __shared__ __align__(16) float  biasO[64];         // out bias

    const int tid  = threadIdx.x;
    const int wave = tid >> 6;          // 0..7
    const int rg   = wave >> 1;         // row-group 0..3
    const int cg   = wave & 1;          // col-group 0..1
    const int lane = tid & 63;
    const int quad = lane >> 4;
    const int l16  = lane & 15;

    const int bb = blockIdx.x >> 6;           // batch
    const int n0 = (blockIdx.x & 63) * COLS;  // column tile base

    // h0 = 0
    for (int i = tid; i < COLS * HH; i += 512) {
        const int col = i >> 7, ch = i & (HH - 1);
        hT[col * SH + ch] = (bf16_t)0.0f;
    }
    // biases -> LDS (pre-scaled)
    if (tid < 256)                 biasG[tid]       = gate_b[tid] * (-LOG2E);
    else if (tid < 384)            biasC[tid - 256] = cand_b[tid - 256] * (-2.0f * LOG2E);
    else if (tid < 448)            biasO[tid - 384] = out_b[tid - 384];

    // ---- weights -> register A-fragments (lane holds A[m0+l16][k0+quad*8+j]) ----
    bf16x8 gA[2][2][6];   // [p: r/z][m'][kt], scaled by -log2e
    #pragma unroll
    for (int p = 0; p < 2; ++p) {
        #pragma unroll
        for (int mm = 0; mm < 2; ++mm) {
            const int m = p * 128 + rg * 32 + mm * 16 + l16;
            #pragma unroll
            for (int kt = 0; kt < 6; ++kt) {
                bf16x8 f;
                #pragma unroll
                for (int j = 0; j < 8; ++j)
                    f[j] = (bf16_t)(gate_w[(m * CC + kt * 32 + quad * 8 + j) * 2 + 1] * (-LOG2E));
                gA[p][mm][kt] = f;
            }
        }
    }
    bf16x8 cA[2][6];      // [m'][kt], scaled by -2*log2e
    #pragma unroll
    for (int mm = 0; mm < 2; ++mm) {
        const int m = rg * 32 + mm * 16 + l16;
        #pragma unroll
        for (int kt = 0; kt < 6; ++kt) {
            bf16x8 f;
            #pragma unroll
            for (int j = 0; j < 8; ++j)
                f[j] = (bf16_t)(cand_w[(m * CC + kt * 32 + quad * 8 + j) * 2 + 1] * (-2.0f * LOG2E));
            cA[mm][kt] = f;
        }
    }
    bf16x8 oA[4];
    {
        const int m = rg * 16 + l16;
        #pragma unroll
        for (int kt = 0; kt < 4; ++kt) {
            bf16x8 f;
            #pragma unroll
            for (int j = 0; j < 8; ++j)
                f[j] = (bf16_t)out_w[m * HH + kt * 32 + quad * 8 + j];
            oA[kt] = f;
        }
    }

    // fp32 master h: hreg[m'][n'][r] = h[rg*32+m'*16+quad*4+r][(2cg+n')*16+l16]
    f32x4 hreg[2][2];
    #pragma unroll
    for (int mm = 0; mm < 2; ++mm)
        #pragma unroll
        for (int nn = 0; nn < 2; ++nn) hreg[mm][nn] = f32x4{0.f, 0.f, 0.f, 0.f};

    const int xcol = tid >> 3;          // 0..63
    const int xcg  = (tid & 7) * 8;     // 8-float group of the 64 features
    const float* xbase = x   + ((size_t)bb * T_ * N_ + n0) * FI;
    float*       obase = out + ((size_t)bb * T_ * N_ + n0) * FI;

    // column base for this wave's reads/writes
    const int c0 = 2 * cg;              // first nt of this wave

    // prologue: load + stage x_0, prefetch x_1
    f32x4 p0 = *(const f32x4*)(xbase + xcol * FI + xcg);
    f32x4 p1 = *(const f32x4*)(xbase + xcol * FI + xcg + 4);
    {
        bf16x8 xv;
        xv[0] = (bf16_t)p0[0]; xv[1] = (bf16_t)p0[1];
        xv[2] = (bf16_t)p0[2]; xv[3] = (bf16_t)p0[3];
        xv[4] = (bf16_t)p1[0]; xv[5] = (bf16_t)p1[1];
        xv[6] = (bf16_t)p1[2]; xv[7] = (bf16_t)p1[3];
        *(bf16x8*)&xT[0][xcol * SX + xcg] = xv;
    }
    {
        const float* xp = xbase + (size_t)1 * N_ * FI + xcol * FI + xcg;
        p0 = *(const f32x4*)xp;
        p1 = *(const f32x4*)(xp + 4);
    }
    BAR();                                             // x_0, h_0, biases ready

    int buf = 0;
    for (int t = 0; t < T_; ++t) {
        const bf16_t* __restrict__ xcur = xT[buf];

        // ---- gates = Wg~ @ [x_t; h_{t-1}]  (4 M-tiles x 2 col-tiles) ----
        f32x4 ar[2][2], az[2][2];
        #pragma unroll
        for (int mm = 0; mm < 2; ++mm) {
            const f32x4 br = *(const f32x4*)&biasG[(2 * rg + mm) * 16 + quad * 4];
            const f32x4 bz = *(const f32x4*)&biasG[128 + (2 * rg + mm) * 16 + quad * 4];
            #pragma unroll
            for (int nn = 0; nn < 2; ++nn) { ar[mm][nn] = br; az[mm][nn] = bz; }
        }
        __builtin_amdgcn_s_setprio(1);
        #pragma unroll
        for (int kt = 0; kt < 6; ++kt) {
            const int ko = kt * 32 + quad * 8;
            #pragma unroll
            for (int nn = 0; nn < 2; ++nn) {
                const int col = (c0 + nn) * 16 + l16;
                bf16x8 b = (kt < 2)
                    ? *(const bf16x8*)&xcur[col * SX + ko]
                    : *(const bf16x8*)&hT[col * SH + (ko - FI)];
                #pragma unroll
                for (int mm = 0; mm < 2; ++mm) {
                    ar[mm][nn] = mfma16(gA[0][mm][kt], b, ar[mm][nn]);
                    az[mm][nn] = mfma16(gA[1][mm][kt], b, az[mm][nn]);
                }
            }
        }
        __builtin_amdgcn_s_setprio(0);

        // sigmoid: sigma = rcp(1 + exp2(gtilde)); r*h -> cT; z stays in registers
        f32x4 zreg[2][2];
        #pragma unroll
        for (int mm = 0; mm < 2; ++mm) {
            #pragma unroll
            for (int nn = 0; nn < 2; ++nn) {
                bf16x4 w;
                #pragma unroll
                for (int r = 0; r < 4; ++r) {
                    const float rr = fast_rcp(1.0f + fast_exp2(ar[mm][nn][r]));
                    zreg[mm][nn][r] = fast_rcp(1.0f + fast_exp2(az[mm][nn][r]));
                    w[r] = (bf16_t)(rr * hreg[mm][nn][r]);
                }
                const int col = (c0 + nn) * 16 + l16;
                *(bf16x4*)&cT[col * SC2 + rg * 32 + mm * 16 + quad * 4] = w;
            }
        }
        BAR();                                         // B_c: r*h ready

        // ---- stage x_{t+1} -> other buffer; prefetch x_{t+2} (overlaps cand) ----
        {
            bf16x8 xv;
            xv[0] = (bf16_t)p0[0]; xv[1] = (bf16_t)p0[1];
            xv[2] = (bf16_t)p0[2]; xv[3] = (bf16_t)p0[3];
            xv[4] = (bf16_t)p1[0]; xv[5] = (bf16_t)p1[1];
            xv[6] = (bf16_t)p1[2]; xv[7] = (bf16_t)p1[3];
            *(bf16x8*)&xT[buf ^ 1][xcol * SX + xcg] = xv;
        }
        {
            const int tn = (t + 2 < T_) ? t + 2 : T_ - 1;
            const float* xp = xbase + (size_t)tn * N_ * FI + xcol * FI + xcg;
            p0 = *(const f32x4*)xp;
            p1 = *(const f32x4*)(xp + 4);
        }

        // ---- cand = Wc~ @ [x_t; r*h] ----
        f32x4 cc[2][2];
        #pragma unroll
        for (int mm = 0; mm < 2; ++mm) {
            const f32x4 bc = *(const f32x4*)&biasC[(2 * rg + mm) * 16 + quad * 4];
            #pragma unroll
            for (int nn = 0; nn < 2; ++nn) cc[mm][nn] = bc;
        }
        __builtin_amdgcn_s_setprio(1);
        #pragma unroll
        for (int kt = 0; kt < 6; ++kt) {
            const int ko = kt * 32 + quad * 8;
            #pragma unroll
            for (int nn = 0; nn < 2; ++nn) {
                const int col = (c0 + nn) * 16 + l16;
                bf16x8 b = (kt < 2)
                    ? *(const bf16x8*)&xcur[col * SX + ko]
                    : *(const bf16x8*)&cT[col * SC2 + (ko - FI)];
                #pragma unroll
                for (int mm = 0; mm < 2; ++mm)
                    cc[mm][nn] = mfma16(cA[mm][kt], b, cc[mm][nn]);
            }
        }
        __builtin_amdgcn_s_setprio(0);

        // tanh(v) = 2*rcp(1+exp2(ctilde)) - 1 ; state update; write bf16 h_t
        #pragma unroll
        for (int mm = 0; mm < 2; ++mm) {
            #pragma unroll
            for (int nn = 0; nn < 2; ++nn) {
                bf16x4 hw;
                #pragma unroll
                for (int r = 0; r < 4; ++r) {
                    const float q  = fast_rcp(1.0f + fast_exp2(cc[mm][nn][r]));
                    const float ht = fmaf(2.0f, q, -1.0f);
                    const float z  = zreg[mm][nn][r];
                    const float h  = hreg[mm][nn][r];
                    const float hn = fmaf(z, ht - h, h);   // (1-z)h + z*ht
                    hreg[mm][nn][r] = hn;
                    hw[r] = (bf16_t)hn;
                }
                const int col = (c0 + nn) * 16 + l16;
                *(bf16x4*)&hT[col * SH + rg * 32 + mm * 16 + quad * 4] = hw;
            }
        }
        BAR();                                         // B_h: h_t (and x_{t+1}) ready

        // ---- o = relu(Wo @ h_t + b) -> direct global store ----
        {
            f32x4 oa[2];
            {
                const f32x4 bo = *(const f32x4*)&biasO[rg * 16 + quad * 4];
                oa[0] = bo; oa[1] = bo;
            }
            __builtin_amdgcn_s_setprio(1);
            #pragma unroll
            for (int kt = 0; kt < 4; ++kt) {
                const int ko = kt * 32 + quad * 8;
                #pragma unroll
                for (int nn = 0; nn < 2; ++nn) {
                    const int col = (c0 + nn) * 16 + l16;
                    bf16x8 b = *(const bf16x8*)&hT[col * SH + ko];
                    oa[nn] = mfma16(oA[kt], b, oa[nn]);
                }
            }
            __builtin_amdgcn_s_setprio(0);
            #pragma unroll
            for (int nn = 0; nn < 2; ++nn) {
                const int col = (c0 + nn) * 16 + l16;
                float* op = obase + (size_t)t * N_ * FI + col * FI + rg * 16 + quad * 4;
                f32x4 o;
                #pragma unroll
                for (int r = 0; r < 4; ++r) o[r] = fmaxf(oa[nn][r], 0.0f);
                *(f32x4*)op = o;
            }
        }
        buf ^= 1;
    }
}

extern "C" void kernel_launch(void* const* d_in, const int* in_sizes, int n_in,
                              void* d_out, int out_size, void* d_ws, size_t ws_size,
                              hipStream_t stream) {
    (void)in_sizes; (void)n_in; (void)d_ws; (void)ws_size; (void)out_size;
    const float* x      = (const float*)d_in[0];
    const float* gate_w = (const float*)d_in[1];
    const float* gate_b = (const float*)d_in[2];
    const float* cand_w = (const float*)d_in[3];
    const float* cand_b = (const float*)d_in[4];
    const float* out_w  = (const float*)d_in[5];
    const float* out_b  = (const float*)d_in[6];
    float* out = (float*)d_out;
    mgru_kernel<<<dim3(B_ * (N_ / COLS)), dim3(512), 0, stream>>>(
        x, gate_w, gate_b, cand_w, cand_b, out_w, out_b, out);
}